// Round 10
// baseline (126.399 us; speedup 1.0000x reference)
//
#include <hip/hip_runtime.h>

#define N 8192
#define Dk 128
#define EPSC 1e-6f
#define MARGIN 0.2f

typedef __attribute__((ext_vector_type(8))) short bf16x8;
typedef __attribute__((ext_vector_type(4))) float f32x4;

__device__ __forceinline__ unsigned short f2bf(float f) {
    unsigned u = __float_as_uint(f);
    u = (u + 0x7FFFu + ((u >> 16) & 1u)) >> 16;  // RNE fp32->bf16
    return (unsigned short)u;
}
// monotone float->uint encoding so atomicMax/Min on unsigned orders like float
__device__ __forceinline__ unsigned enc(float f) {
    unsigned u = __float_as_uint(f);
    return (u & 0x80000000u) ? ~u : (u | 0x80000000u);
}
__device__ __forceinline__ float dec(unsigned u) {
    return __uint_as_float((u & 0x80000000u) ? (u & 0x7FFFFFFFu) : ~u);
}

// Kernel A: SWIZZLED bf16 copy of x (16B chunk c of row r stored at chunk c^(r&7)),
// per-row P and QT (-Q/2, class), stat init. One wave per row. (Swizzle kept:
// with the XOR pattern each 64B line is still read by exactly 4 lanes at full
// utilization -> no coalescing penalty, and prep stays identical/proven.)
__global__ void prep_kernel(const float* __restrict__ x, const int* __restrict__ tgt,
                            unsigned short* __restrict__ Xb, uint2* __restrict__ QT,
                            float* __restrict__ P,
                            unsigned* __restrict__ wsHp, unsigned* __restrict__ wsMn) {
    int row = blockIdx.x * 4 + (threadIdx.x >> 6);
    int l = threadIdx.x & 63;
    const float2 v = *reinterpret_cast<const float2*>(&x[row * Dk + l * 2]);
    float sq = fmaf(v.x, v.x, v.y * v.y);
    float s = v.x + v.y;
    ushort2 a;
    a.x = f2bf(v.x);
    a.y = f2bf(v.y);
    int c_phys = (l >> 2) ^ (row & 7);
    *reinterpret_cast<ushort2*>(&Xb[row * Dk + c_phys * 8 + 2 * (l & 3)]) = a;
#pragma unroll
    for (int m = 32; m >= 1; m >>= 1) {
        sq += __shfl_xor(sq, m);
        s += __shfl_xor(s, m);
    }
    if (l == 0) {
        P[row] = sq - 2.0f * EPSC * s;
        float Qj = sq + 2.0f * EPSC * s + (float)Dk * EPSC * EPSC;
        uint2 qt;
        qt.x = __float_as_uint(-0.5f * Qj);
        qt.y = (unsigned)tgt[row];
        QT[row] = qt;
        wsHp[row] = 0xFF800000u;  // enc(+inf): identity for MIN (hardest_pos = min acc)
        wsMn[row] = 0x007FFFFFu;  // enc(-inf): identity for MAX (hardest_neg = max acc)
    }
}

// Kernel B round 10: BARRIER-FREE SELF-PACED WAVES. 10 rounds showed main pinned
// at 40-50us regardless of LDS volume, occupancy, barrier type, epilogue weight,
// or total FLOPs (R9 halving: neutral) -- ~90% per-step stall with no pipe >37%.
// Remaining suspect: the cross-wave convoy of cooperative-LDS + s_barrier (every
// wave chained to 3 others; 1024 identical blocks in phase; m233: the 2-phase
// stage/vmcnt/barrier structure carries ~72% overhead that piecewise fixes don't
// remove). Test: eliminate ALL synchronization. B is 2MB = L2-resident, so each
// wave loads its own B fragments global->REGS (consumer==producer; no LDS, no
// barrier, nothing shared). 4096 independent 1-wave blocks: 32 rows x 512 cols
// each, 16 steps of 32 cols. 2-step-deep register pipeline (BpA/BpB + qtA/qtB,
// STATIC indexing via even/odd step bodies -- rule #20), QT prefetched with B.
// This is round-1's no-LDS design with its two diagnosed failures fixed:
// lookahead 4 loads -> 2 full steps (~500cy >= L2 latency), occupancy 2 -> 3
// waves/SIMD (~165 regs, launch_bounds(64,3)). L2 floor 512MB/34.5TBs = 15us.
// acc init = -Q_j/2 => acc = dot - Q_j/2; d2 = P_i - 2*acc (monotone decreasing):
// hardest_pos = min acc over same-class, hardest_neg = max acc over diff-class.
__global__ __launch_bounds__(64, 3) void main_kernel(
        const unsigned short* __restrict__ Xb,
        const uint2* __restrict__ QT, const int* __restrict__ tgt,
        unsigned* __restrict__ wsHp, unsigned* __restrict__ wsMn) {
    const int lane = threadIdx.x;
    const int n = lane & 15;
    const int q = lane >> 4;
    const int sw = n & 7;  // swizzle key: (global row)&7 == n&7 for rows this lane reads

    const int wid = (int)blockIdx.x;  // 4096 waves
    const int rg = wid >> 4;          // 0..255: row group of 32
    const int cs = wid & 15;          // 0..15 : col slice of 512
    const int rbase = rg * 32;
    const int jb0 = cs * 512;

    const bf16x8* Xv = reinterpret_cast<const bf16x8*>(Xb);

    // Persistent A fragments: 32 rows x K=128 (32 VGPRs)
    bf16x8 Af[2][4];
#pragma unroll
    for (int ti = 0; ti < 2; ++ti)
#pragma unroll
        for (int kk = 0; kk < 4; ++kk)
            Af[ti][kk] = Xv[(rbase + 16 * ti + n) * 16 + ((q + 4 * kk) ^ sw)];

    // anchor classes for this lane's 8 row-slots: row = rbase + 16*ti + 4*q + r
    int tsl[8];
#pragma unroll
    for (int ti = 0; ti < 2; ++ti) {
        int4 t4 = *reinterpret_cast<const int4*>(&tgt[rbase + 16 * ti + 4 * q]);
        tsl[4 * ti + 0] = t4.x;
        tsl[4 * ti + 1] = t4.y;
        tsl[4 * ti + 2] = t4.z;
        tsl[4 * ti + 3] = t4.w;
    }

    float hp[8], mn[8];
#pragma unroll
    for (int s = 0; s < 8; ++s) {
        hp[s] = INFINITY;
        mn[s] = -INFINITY;
    }

    // 2-step register pipeline for B fragments + QT (static even/odd state)
    bf16x8 BpA[4][2], BpB[4][2];  // [kk][tj], 32 VGPR each
    uint2 qtA[2], qtB[2];

    auto loadB = [&](int s, bf16x8(&Bp)[4][2], uint2(&qt)[2]) {
        const int jb = jb0 + s * 32;
#pragma unroll
        for (int kk = 0; kk < 4; ++kk)
#pragma unroll
            for (int tj = 0; tj < 2; ++tj)
                Bp[kk][tj] = Xv[(jb + 16 * tj + n) * 16 + ((q + 4 * kk) ^ sw)];
#pragma unroll
        for (int tj = 0; tj < 2; ++tj) qt[tj] = QT[jb + 16 * tj + n];
    };

    // one step: consume (Bp,qt) for step s, then reload same regs with step s+2
    auto STEP = [&](int s, bf16x8(&Bp)[4][2], uint2(&qt)[2]) {
        float Qv[2];
        int tv[2];
#pragma unroll
        for (int tj = 0; tj < 2; ++tj) {
            Qv[tj] = __uint_as_float(qt[tj].x);  // = -Q_j/2
            tv[tj] = (int)qt[tj].y;
        }

        f32x4 acc[2][2];
#pragma unroll
        for (int ti = 0; ti < 2; ++ti)
#pragma unroll
            for (int tj = 0; tj < 2; ++tj) acc[ti][tj] = Qv[tj];

        __builtin_amdgcn_s_setprio(1);
#pragma unroll
        for (int kk = 0; kk < 4; ++kk)
#pragma unroll
            for (int ti = 0; ti < 2; ++ti)
#pragma unroll
                for (int tj = 0; tj < 2; ++tj)
                    acc[ti][tj] = __builtin_amdgcn_mfma_f32_16x16x32_bf16(
                        Af[ti][kk], Bp[kk][tj], acc[ti][tj], 0, 0, 0);
        __builtin_amdgcn_s_setprio(0);

        // prefetch step s+2 into the just-consumed regs (WAR: loads issue after
        // the MFMAs that read Bp; data lands during epilogue + next step)
        if (s + 2 < 16) loadB(s + 2, Bp, qt);

        // epilogue: acc elem r is (row rbase+16ti+4q+r, col jb0+32s+16tj+n)
        const int jb = jb0 + s * 32;
        (void)jb;
#pragma unroll
        for (int tj = 0; tj < 2; ++tj) {
            int tvv = tv[tj];
#pragma unroll
            for (int ti = 0; ti < 2; ++ti) {
                f32x4 v = acc[ti][tj];
                int e0 = tvv == tsl[4 * ti + 0];
                int e1 = tvv == tsl[4 * ti + 1];
                int e2 = tvv == tsl[4 * ti + 2];
                int e3 = tvv == tsl[4 * ti + 3];
                if (__ballot(e0 | e1 | e2 | e3)) {  // same-class pairs present (~rare)
                    hp[4 * ti + 0] = fminf(hp[4 * ti + 0], e0 ? v[0] : INFINITY);
                    hp[4 * ti + 1] = fminf(hp[4 * ti + 1], e1 ? v[1] : INFINITY);
                    hp[4 * ti + 2] = fminf(hp[4 * ti + 2], e2 ? v[2] : INFINITY);
                    hp[4 * ti + 3] = fminf(hp[4 * ti + 3], e3 ? v[3] : INFINITY);
                    mn[4 * ti + 0] = fmaxf(mn[4 * ti + 0], e0 ? -INFINITY : v[0]);
                    mn[4 * ti + 1] = fmaxf(mn[4 * ti + 1], e1 ? -INFINITY : v[1]);
                    mn[4 * ti + 2] = fmaxf(mn[4 * ti + 2], e2 ? -INFINITY : v[2]);
                    mn[4 * ti + 3] = fmaxf(mn[4 * ti + 3], e3 ? -INFINITY : v[3]);
                } else {  // all-diff-class fast path
                    mn[4 * ti + 0] = fmaxf(mn[4 * ti + 0], v[0]);
                    mn[4 * ti + 1] = fmaxf(mn[4 * ti + 1], v[1]);
                    mn[4 * ti + 2] = fmaxf(mn[4 * ti + 2], v[2]);
                    mn[4 * ti + 3] = fmaxf(mn[4 * ti + 3], v[3]);
                }
            }
        }
    };

    loadB(0, BpA, qtA);
    loadB(1, BpB, qtB);

    for (int s = 0; s < 16; s += 2) {  // not fully unrolled (R8: unroll bloat hurt)
        STEP(s, BpA, qtA);
        STEP(s + 1, BpB, qtB);
    }

    // reduce across the 16 col-lanes; lane n==0 of each quad commits rows 4q+r
#pragma unroll
    for (int m = 1; m <= 8; m <<= 1) {
#pragma unroll
        for (int s = 0; s < 8; ++s) {
            hp[s] = fminf(hp[s], __shfl_xor(hp[s], m));
            mn[s] = fmaxf(mn[s], __shfl_xor(mn[s], m));
        }
    }
    if (n == 0) {
#pragma unroll
        for (int ti = 0; ti < 2; ++ti) {
#pragma unroll
            for (int r = 0; r < 4; ++r) {
                int i = rbase + 16 * ti + 4 * q + r;
                atomicMin(&wsHp[i], enc(hp[4 * ti + r]));
                atomicMax(&wsMn[i], enc(mn[4 * ti + r]));
            }
        }
    }
}

// Kernel C: single block, vectorized loads, writes out directly
__global__ void finish_kernel(const float* __restrict__ P,
                              const unsigned* __restrict__ wsHp,
                              const unsigned* __restrict__ wsMn,
                              float* __restrict__ out) {
    int t = threadIdx.x;  // 1024 threads, thread t handles i in [8t, 8t+8)
    float sum = 0.0f;
#pragma unroll
    for (int h = 0; h < 2; ++h) {
        int base = 8 * t + 4 * h;
        float4 Pv = *reinterpret_cast<const float4*>(&P[base]);
        uint4 Hv = *reinterpret_cast<const uint4*>(&wsHp[base]);
        uint4 Mv = *reinterpret_cast<const uint4*>(&wsMn[base]);
        const float* Pf = &Pv.x;
        const unsigned* Hu = &Hv.x;
        const unsigned* Mu = &Mv.x;
#pragma unroll
        for (int k = 0; k < 4; ++k) {
            float hp = sqrtf(fmaxf(fmaf(-2.0f, dec(Hu[k]), Pf[k]), 0.0f));
            float hn = sqrtf(fmaxf(fmaf(-2.0f, dec(Mu[k]), Pf[k]), 0.0f));
            sum += fmaxf(hp - hn + MARGIN, 0.0f);
        }
    }
#pragma unroll
    for (int m = 32; m >= 1; m >>= 1) sum += __shfl_xor(sum, m);
    __shared__ float ws[16];
    if ((t & 63) == 0) ws[t >> 6] = sum;
    __syncthreads();
    if (t == 0) {
        float tot = 0.0f;
#pragma unroll
        for (int i = 0; i < 16; ++i) tot += ws[i];
        out[0] = tot * (1.0f / (float)N);
    }
}

extern "C" void kernel_launch(void* const* d_in, const int* in_sizes, int n_in,
                              void* d_out, int out_size, void* d_ws, size_t ws_size,
                              hipStream_t stream) {
    const float* x = (const float*)d_in[0];
    const int* tgt = (const int*)d_in[1];
    float* out = (float*)d_out;

    char* ws = (char*)d_ws;
    const size_t xb = (size_t)N * Dk * 2;  // 2 MB swizzled bf16 copy
    unsigned short* Xb = (unsigned short*)ws;
    uint2* QT = (uint2*)(ws + xb);
    float* P = (float*)(ws + xb + (size_t)N * 8);
    unsigned* wsHp = (unsigned*)(ws + xb + (size_t)N * 12);
    unsigned* wsMn = (unsigned*)(ws + xb + (size_t)N * 16);

    prep_kernel<<<N / 4, 256, 0, stream>>>(x, tgt, Xb, QT, P, wsHp, wsMn);
    main_kernel<<<4096, 64, 0, stream>>>(Xb, QT, tgt, wsHp, wsMn);
    finish_kernel<<<1, 1024, 0, stream>>>(P, wsHp, wsMn, out);
}